// Round 9
// baseline (617.271 us; speedup 1.0000x reference)
//
#include <hip/hip_runtime.h>
#include <cmath>

typedef __attribute__((ext_vector_type(8))) _Float16 f16x8;
typedef __attribute__((ext_vector_type(4))) float f32x4;
typedef __attribute__((ext_vector_type(4))) unsigned u32x4;

#define REC_NB 32
#define HEAD_NB 192

__device__ __forceinline__ unsigned short f2h(float x) {
  return __builtin_bit_cast(unsigned short, (_Float16)x);
}

__device__ __forceinline__ void gload16(const void* g, void* l) {
  __builtin_amdgcn_global_load_lds(
      (const __attribute__((address_space(1))) void*)g,
      (__attribute__((address_space(3))) void*)l, 16, 0, 0);
}

// Coherent (cache-bypassing) coalesced 16B load — round-7-proven mechanism
// for reading same-dispatch agent-atomic stores.
__device__ __forceinline__ void cload16(const void* p, u32x4* dst) {
  asm volatile("global_load_dwordx4 %0, %1, off sc0 sc1"
               : "=v"(*dst)
               : "v"(p));
}

// ============================================================================
// Stage 1: fused conv1 + relu + maxpool2x2 + conv2 + relu + spatial-sum.
// ============================================================================
__global__ __launch_bounds__(512) void k_conv(
    const float* __restrict__ mask, const float* __restrict__ w1,
    const float* __restrict__ b1, const float* __restrict__ w2,
    const float* __restrict__ b2, float* __restrict__ part)
{
  __shared__ float s_p1[16][18 * 36];
  __shared__ float s_w1[144];
  __shared__ float s_b1[16];
  __shared__ float s_w2[4608];
  __shared__ float s_b2[32];

  const int tid = threadIdx.x;
  const int b = blockIdx.x >> 5;
  const int tile = blockIdx.x & 31;
  const int px0 = (tile & 3) * 32, py0 = (tile >> 2) * 16;
  const float* mb = mask + (size_t)b * 65536;

  for (int i = tid; i < 144; i += 512) s_w1[i] = w1[i];
  for (int i = tid; i < 4608; i += 512) s_w2[i] = w2[i];
  if (tid < 16) s_b1[tid] = b1[tid];
  if (tid < 32) s_b2[tid] = b2[tid];
  __syncthreads();

  for (int idx = tid; idx < 18 * 34; idx += 512) {
    int ly = idx / 34, lx = idx - ly * 34;
    int py = py0 - 1 + ly, px = px0 - 1 + lx;
    if (py < 0 || py >= 128 || px < 0 || px >= 128) {
      for (int o = 0; o < 16; o++) s_p1[o][ly * 36 + lx] = 0.f;
    } else {
      float patch[4][4];
      int gy0 = 2 * py - 1, gx0 = 2 * px - 1;
#pragma unroll
      for (int i = 0; i < 4; i++) {
        int gy = gy0 + i;
        bool yok = (gy >= 0 && gy < 256);
#pragma unroll
        for (int j = 0; j < 4; j++) {
          int gx = gx0 + j;
          patch[i][j] = (yok && gx >= 0 && gx < 256) ? mb[gy * 256 + gx] : 0.f;
        }
      }
      for (int o = 0; o < 16; o++) {
        float m = 0.f;
#pragma unroll
        for (int dy = 0; dy < 2; dy++)
#pragma unroll
          for (int dx = 0; dx < 2; dx++) {
            float v = s_b1[o];
#pragma unroll
            for (int ky = 0; ky < 3; ky++)
#pragma unroll
              for (int kx = 0; kx < 3; kx++)
                v = fmaf(patch[dy + ky][dx + kx], s_w1[o * 9 + ky * 3 + kx], v);
            m = fmaxf(m, v);
          }
        s_p1[o][ly * 36 + lx] = m;
      }
    }
  }
  __syncthreads();

  const int ocg = tid >> 6;
  const int sp = tid & 63;
  const int sx = (sp & 7) * 4, sy = (sp >> 3) * 2;
  float acc[4][8];
#pragma unroll
  for (int a = 0; a < 4; a++)
#pragma unroll
    for (int q = 0; q < 8; q++) acc[a][q] = 0.f;

  for (int ic = 0; ic < 16; ic++) {
    float p[4][6];
#pragma unroll
    for (int i = 0; i < 4; i++) {
      const float* row = &s_p1[ic][(sy + i) * 36 + sx];
#pragma unroll
      for (int j = 0; j < 6; j++) p[i][j] = row[j];
    }
#pragma unroll
    for (int o4 = 0; o4 < 4; o4++) {
      const int oc = ocg * 4 + o4;
      const float* w = &s_w2[(oc * 16 + ic) * 9];
      float w00 = w[0], w01 = w[1], w02 = w[2];
      float w10 = w[3], w11 = w[4], w12 = w[5];
      float w20 = w[6], w21 = w[7], w22 = w[8];
#pragma unroll
      for (int y = 0; y < 2; y++)
#pragma unroll
        for (int x = 0; x < 4; x++) {
          float s = acc[o4][y * 4 + x];
          s = fmaf(p[y][x], w00, s);
          s = fmaf(p[y][x + 1], w01, s);
          s = fmaf(p[y][x + 2], w02, s);
          s = fmaf(p[y + 1][x], w10, s);
          s = fmaf(p[y + 1][x + 1], w11, s);
          s = fmaf(p[y + 1][x + 2], w12, s);
          s = fmaf(p[y + 2][x], w20, s);
          s = fmaf(p[y + 2][x + 1], w21, s);
          s = fmaf(p[y + 2][x + 2], w22, s);
          acc[o4][y * 4 + x] = s;
        }
    }
  }

  const int lane = tid & 63;
#pragma unroll
  for (int o4 = 0; o4 < 4; o4++) {
    float bv = s_b2[ocg * 4 + o4];
    float s = 0.f;
#pragma unroll
    for (int q = 0; q < 8; q++) s += fmaxf(acc[o4][q] + bv, 0.f);
    for (int off = 32; off > 0; off >>= 1) s += __shfl_down(s, off, 64);
    if (lane == 0) part[(b * 32 + tile) * 32 + ocg * 4 + o4] = s;
  }
}

// ============================================================================
// Stage 2a: tile partials -> pooled mean -> h0 GEMM (K=32).
// ============================================================================
__global__ __launch_bounds__(256) void k_pool_h0(
    const float* __restrict__ part, const float* __restrict__ feat_w,
    const float* __restrict__ feat_b, float* __restrict__ h0,
    unsigned short* __restrict__ h0f)
{
  const int b = blockIdx.x, tid = threadIdx.x;
  __shared__ float pl[32];
  if (tid < 32) {
    float s = 0.f;
    for (int t = 0; t < 32; t++) s += part[(b * 32 + t) * 32 + tid];
    pl[tid] = s * (1.0f / 16384.0f);
  }
  __syncthreads();
  for (int j = tid; j < 512; j += 256) {
    float acc = feat_b[j];
    const float* w = feat_w + j * 32;
#pragma unroll
    for (int ic = 0; ic < 32; ic++) acc = fmaf(pl[ic], w[ic], acc);
    h0[b * 512 + j] = acc;
    h0f[b * 512 + j] = f2h(acc);
  }
}

// ============================================================================
// Stage 2b: ctx = h0 @ ctx_w.T + ctx_b.
// ============================================================================
__global__ __launch_bounds__(256) void k_ctx(
    const float* __restrict__ h0, const float* __restrict__ ctx_w,
    const float* __restrict__ ctx_b, float* __restrict__ ctx)
{
  const int b = blockIdx.x, tid = threadIdx.x;
  __shared__ float hs[512];
  for (int k = tid; k < 512; k += 256) hs[k] = h0[b * 512 + k];
  __syncthreads();
  for (int j = tid; j < 512; j += 256) {
    const float* w = ctx_w + (size_t)j * 512;
    float s0 = 0.f, s1 = 0.f, s2 = 0.f, s3 = 0.f;
    for (int k = 0; k < 512; k += 4) {
      float4 w4 = *(const float4*)(w + k);
      s0 = fmaf(hs[k], w4.x, s0);
      s1 = fmaf(hs[k + 1], w4.y, s1);
      s2 = fmaf(hs[k + 2], w4.z, s2);
      s3 = fmaf(hs[k + 3], w4.w, s3);
    }
    ctx[b * 512 + j] = ctx_b[j] + ((s0 + s1) + (s2 + s3));
  }
}

// ============================================================================
// fp32 -> f16 (RNE), 4 elems/thread.
// ============================================================================
__global__ __launch_bounds__(256) void k_f2h(
    const float* __restrict__ in, unsigned short* __restrict__ out, int n)
{
  int i = (blockIdx.x * 256 + threadIdx.x) * 4;
  if (i < n) {
    float4 v = *(const float4*)(in + i);
    unsigned lo = (unsigned)f2h(v.x) | ((unsigned)f2h(v.y) << 16);
    unsigned hi = (unsigned)f2h(v.z) | ((unsigned)f2h(v.w) << 16);
    *(uint2*)(out + i) = make_uint2(lo, hi);
  }
}

// ============================================================================
// Zero helpers (ws poisoned to 0xAA before timing; re-init every call).
// ============================================================================
__global__ __launch_bounds__(256) void k_zero_i(int* __restrict__ p, int n) {
  int i = blockIdx.x * 256 + threadIdx.x;
  if (i < n) p[i] = 0;
}
__global__ __launch_bounds__(256) void k_zero_f(float* __restrict__ p) {
  p[blockIdx.x * 256 + threadIdx.x] = 0.f;
}

// ============================================================================
// Stage 3a: A[(t*64+b)][k] = f16(tok_emb[tok][k] + ctx[b][k])
// ============================================================================
__global__ __launch_bounds__(128) void k_build_A(
    const float* __restrict__ tok_emb, const int* __restrict__ tgt,
    const float* __restrict__ ctx, unsigned short* __restrict__ A)
{
  const int r = blockIdx.x;
  const int t = r >> 6, b = r & 63;
  const int tok = (t == 0) ? 4096 : tgt[b * 50 + (t - 1)];
  const int i = threadIdx.x * 4;
  float4 ev = *(const float4*)(tok_emb + (size_t)tok * 512 + i);
  float4 cv = *(const float4*)(ctx + b * 512 + i);
  unsigned lo = (unsigned)f2h(ev.x + cv.x) | ((unsigned)f2h(ev.y + cv.y) << 16);
  unsigned hi = (unsigned)f2h(ev.z + cv.z) | ((unsigned)f2h(ev.w + cv.w) << 16);
  *(uint2*)(A + (size_t)r * 512 + i) = make_uint2(lo, hi);
}

// ============================================================================
// f16 MFMA GEMM (m97 structure): C(MxN) = A(Mx512) @ B(Nx512)^T + bias.
// MODE 0: xgates; C TRANSPOSED (t, gate-dd, b) = (50,2048,64).
// MODE 1: head (fallback path only); C remapped (t*64+b, v) -> (b*50+t, v).
// ============================================================================
template <int MODE>
__global__ __launch_bounds__(256) void k_gemm_mfma(
    const unsigned short* __restrict__ A, const unsigned short* __restrict__ B,
    const float* __restrict__ bias_a, const float* __restrict__ bias_b,
    float* __restrict__ C, int NB)
{
  __shared__ unsigned short sA[128 * 32];
  __shared__ unsigned short sB[128 * 32];
  const int tid = threadIdx.x;
  const int bx = blockIdx.x % NB, by = blockIdx.x / NB;
  const int lane = tid & 63, wv = tid >> 6;
  const int wr = wv >> 1, wc = wv & 1;
  const unsigned short* Ab = A + (size_t)by * 128 * 512;
  const unsigned short* Bb = B + (size_t)bx * 128 * 512;

  f32x4 acc[4][4];
#pragma unroll
  for (int m = 0; m < 4; m++)
#pragma unroll
    for (int n = 0; n < 4; n++) acc[m][n] = (f32x4){0.f, 0.f, 0.f, 0.f};

  const int r0 = tid >> 2, c0 = (tid & 3) * 8;
  const int idx1 = tid + 256;
  const int r1 = idx1 >> 2, c1 = (idx1 & 3) * 8;
  unsigned short* lA0 = sA + (size_t)wv * 512;
  unsigned short* lA1 = sA + 2048 + (size_t)wv * 512;
  unsigned short* lB0 = sB + (size_t)wv * 512;
  unsigned short* lB1 = sB + 2048 + (size_t)wv * 512;

  const int frow = lane & 15;
  const int foff = (lane >> 4) * 8;

  for (int kc = 0; kc < 512; kc += 32) {
    gload16(Ab + (size_t)r0 * 512 + kc + c0, lA0);
    gload16(Ab + (size_t)r1 * 512 + kc + c1, lA1);
    gload16(Bb + (size_t)r0 * 512 + kc + c0, lB0);
    gload16(Bb + (size_t)r1 * 512 + kc + c1, lB1);
    __syncthreads();

    f16x8 af[4], bfr[4];
#pragma unroll
    for (int m = 0; m < 4; m++)
      af[m] = *(const f16x8*)(sA + (wr * 64 + m * 16 + frow) * 32 + foff);
#pragma unroll
    for (int n = 0; n < 4; n++)
      bfr[n] = *(const f16x8*)(sB + (wc * 64 + n * 16 + frow) * 32 + foff);
#pragma unroll
    for (int m = 0; m < 4; m++)
#pragma unroll
      for (int n = 0; n < 4; n++)
        acc[m][n] = __builtin_amdgcn_mfma_f32_16x16x32_f16(
            af[m], bfr[n], acc[m][n], 0, 0, 0);
    __syncthreads();
  }

#pragma unroll
  for (int n = 0; n < 4; n++) {
    const int gc = bx * 128 + wc * 64 + n * 16 + (lane & 15);
    const float bv = (MODE == 0) ? (bias_a[gc] + bias_b[gc]) : bias_a[gc];
#pragma unroll
    for (int m = 0; m < 4; m++) {
      const int rb = by * 128 + wr * 64 + m * 16 + (lane >> 4) * 4;
#pragma unroll
      for (int j = 0; j < 4; j++) {
        const int r = rb + j;
        float v = acc[m][n][j] + bv;
        int t = r >> 6, bb = r & 63;
        if (MODE == 0) {
          C[(size_t)t * 131072 + (size_t)gc * 64 + bb] = v;
        } else {
          C[((size_t)bb * 50 + t) * 4096 + gc] = v;
        }
      }
    }
  }
}

// ============================================================================
// Stage 4 (primary): PERSISTENT LSTM + FUSED HEAD GEMM, one cooperative
// dispatch, 224 blocks = 32 recurrence + 192 head consumers.
//  - Recurrence (blocks 0..31): round-8-proven f16 MFMA structure; barrier
//    upgraded to a flag array (store own flag, 32 lanes poll in parallel —
//    no RMW round-trip, exit one load-latency after last arrival).
//  - Head (blocks 32..223): block owns a 64-col vocab tile (B-frags preloaded
//    ONCE into 64 VGPRs; B constant across t) x ~17 timesteps. Polls flags[t],
//    stages hallf[t] via coherent loads (round-7 mechanism), 64 MFMAs/wave,
//    writes d_out directly. Head work hides entirely inside the step cadence
//    -> the separate head-GEMM dispatch disappears.
// ============================================================================
__global__ __launch_bounds__(256, 1) void k_lstm_head(
    const float* __restrict__ xgT,            // (50,2048,64) xgates (biased)
    const float* __restrict__ w_hh,           // (2048,512) fp32
    const unsigned short* __restrict__ h0f,   // (64,512) f16
    unsigned short* __restrict__ hallf,       // (50,64,512) f16 h history
    const unsigned short* __restrict__ hwb,   // (4096,512) f16 head weights
    const float* __restrict__ head_b,         // (4096)
    float* __restrict__ out,                  // (64,50,4096)
    int* __restrict__ flags)                  // 50*32 ints, zeroed
{
  __shared__ unsigned short s_h[64 * 512];    // 64 KB, XOR-swizzled rows
  __shared__ float s_g[4][64][17];            // rec only, 17.4 KB
  const int tid = threadIdx.x;
  const int lane = tid & 63;
  const int frow = lane & 15;
  const int foff = (lane >> 4) * 8;

  if (blockIdx.x < REC_NB) {
    // ======================= recurrence =======================
    const int kb = blockIdx.x;      // dims [16*kb, 16*kb+16)
    const int g = tid >> 6;         // gate = wave

    f16x8 wf[16];
    {
      const float* wrow = w_hh + (size_t)(g * 512 + kb * 16 + frow) * 512;
#pragma unroll
      for (int kf = 0; kf < 16; kf++) {
        float tmp[8];
        *(float4*)tmp = *(const float4*)(wrow + kf * 32 + foff);
        *(float4*)(tmp + 4) = *(const float4*)(wrow + kf * 32 + foff + 4);
#pragma unroll
        for (int j = 0; j < 8; j++) wf[kf][j] = (_Float16)tmp[j];
      }
    }

    float c[4] = {0.f, 0.f, 0.f, 0.f};
    const int b2 = tid & 63, dd2 = tid >> 6;

    for (int t = 0; t < 50; ++t) {
      const unsigned short* H = t ? hallf + (size_t)(t - 1) * 32768 : h0f;

      const float* xr =
          xgT + (size_t)t * 131072 + (size_t)(kb * 16 + dd2 * 4) * 64 + b2;
      float xv[16];
#pragma unroll
      for (int gq = 0; gq < 4; gq++)
#pragma unroll
        for (int i = 0; i < 4; i++)
          xv[gq * 4 + i] = xr[(size_t)(gq * 512 + i) * 64];

      {
        u32x4 r[16];
#pragma unroll
        for (int i = 0; i < 16; i++)
          cload16((const char*)H + (size_t)(tid + i * 256) * 16, &r[i]);
        asm volatile("s_waitcnt vmcnt(0)" ::: "memory");
        __builtin_amdgcn_sched_barrier(0);
#pragma unroll
        for (int i = 0; i < 16; i++) {
          int byte = (tid + i * 256) * 16;
          int swz = byte ^ (((byte >> 10) & 7) << 4);
          *(u32x4*)((char*)s_h + swz) = r[i];
        }
      }
      __syncthreads();

      f32x4 acc[4];
#pragma unroll
      for (int mt = 0; mt < 4; mt++) acc[mt] = (f32x4){0.f, 0.f, 0.f, 0.f};
#pragma unroll
      for (int kf = 0; kf < 16; kf++) {
#pragma unroll
        for (int mt = 0; mt < 4; mt++) {
          const int row = mt * 16 + frow;
          const int byte = (row << 10) + kf * 64 + foff * 2;
          const int swz = byte ^ ((row & 7) << 4);
          f16x8 ah = *(const f16x8*)((const char*)s_h + swz);
          acc[mt] = __builtin_amdgcn_mfma_f32_16x16x32_f16(ah, wf[kf],
                                                           acc[mt], 0, 0, 0);
        }
      }
#pragma unroll
      for (int mt = 0; mt < 4; mt++)
#pragma unroll
        for (int j = 0; j < 4; j++)
          s_g[g][mt * 16 + (lane >> 4) * 4 + j][frow] = acc[mt][j];
      __syncthreads();

      unsigned long long qf = 0;
#pragma unroll
      for (int i = 0; i < 4; i++) {
        float gi = s_g[0][b2][dd2 * 4 + i] + xv[0 + i];
        float gf = s_g[1][b2][dd2 * 4 + i] + xv[4 + i];
        float gg = s_g[2][b2][dd2 * 4 + i] + xv[8 + i];
        float go = s_g[3][b2][dd2 * 4 + i] + xv[12 + i];
        float ig = 1.f / (1.f + expf(-gi));
        float fg = 1.f / (1.f + expf(-gf));
        float og = 1.f / (1.f + expf(-go));
        float gt = tanhf(gg);
        c[i] = fmaf(fg, c[i], ig * gt);
        float h = og * tanhf(c[i]);
        qf |= (unsigned long long)f2h(h) << (16 * i);
      }
      const size_t ho = (size_t)b2 * 512 + kb * 16 + dd2 * 4;
      __hip_atomic_store((unsigned long long*)(hallf + (size_t)t * 32768 + ho),
                         qf, __ATOMIC_RELAXED, __HIP_MEMORY_SCOPE_AGENT);
      __syncthreads();  // drains vmcnt(0) on every wave -> stores visible

      // Flag barrier: announce, then (except last step) wait for all peers.
      if (tid == 0)
        __hip_atomic_store(&flags[t * 32 + kb], 1, __ATOMIC_RELAXED,
                           __HIP_MEMORY_SCOPE_AGENT);
      if (t < 49 && tid < 32) {
        while (__hip_atomic_load(&flags[t * 32 + tid], __ATOMIC_RELAXED,
                                 __HIP_MEMORY_SCOPE_AGENT) == 0) {
          __builtin_amdgcn_s_sleep(1);
        }
      }
      __syncthreads();
    }
  } else {
    // ======================= head consumers =======================
    const int hb = blockIdx.x - REC_NB;  // 0..191
    const int ct = hb % 64;              // 64-col vocab tile
    const int tg = hb / 64;              // time phase 0..2
    const int wv = tid >> 6;

    // Preload B fragments once (constant across t): 16 frags = 64 VGPRs.
    f16x8 bf[16];
    const unsigned short* brow =
        hwb + (size_t)(ct * 64 + wv * 16 + frow) * 512;
#pragma unroll
    for (int kf = 0; kf < 16; kf++)
      bf[kf] = *(const f16x8*)(brow + kf * 32 + foff);
    const float bias = head_b[ct * 64 + wv * 16 + frow];

    for (int t = tg; t < 50; t += 3) {
      // Wait until all 32 recurrence blocks finished step t.
      if (tid < 32) {
        while (__hip_atomic_load(&flags[t * 32 + tid], __ATOMIC_RELAXED,
                                 __HIP_MEMORY_SCOPE_AGENT) == 0) {
          __builtin_amdgcn_s_sleep(1);
        }
      }
      __syncthreads();

      // Stage A = hallf[t] (coherent, swizzled) into s_h.
      {
        const char* src = (const char*)(hallf + (size_t)t * 32768);
        u32x4 r[16];
#pragma unroll
        for (int i = 0; i < 16; i++)
          cload16(src + (size_t)(tid + i * 256) * 16, &r[i]);
        asm volatile("s_waitcnt vmcnt(0)" ::: "memory");
        __builtin_amdgcn_sched_barrier(0);
#pragma unroll
        for (int i = 0; i < 16; i++) {
          int byte = (tid + i * 256) * 16;
          int swz = byte ^ (((byte >> 10) & 7) << 4);
          *(u32x4*)((char*)s_h + swz) = r[i];
        }
      }
      __syncthreads();

      // 64 MFMAs/wave: D[batch, 16-col slice].
      f32x4 acc[4];
#pragma unroll
      for (int m = 0; m < 4; m++) acc[m] = (f32x4){0.f, 0.f, 0.f, 0.f};
#pragma unroll
      for (int kf = 0; kf < 16; kf++) {
#pragma unroll
        for (int m = 0; m < 4; m++) {
          const int row = m * 16 + frow;
          const int byte = (row << 10) + kf * 64 + foff * 2;
          const int swz = byte ^ ((row & 7) << 4);
          f16x8 ah = *(const f16x8*)((const char*)s_h + swz);
          acc[m] = __builtin_amdgcn_mfma_f32_16x16x32_f16(ah, bf[kf], acc[m],
                                                          0, 0, 0);
        }
      }
      // Epilogue: C/D col = lane&15, row = (lane>>4)*4 + j (batch).
      const int gc = ct * 64 + wv * 16 + (lane & 15);
#pragma unroll
      for (int m = 0; m < 4; m++) {
#pragma unroll
        for (int j = 0; j < 4; j++) {
          const int b = m * 16 + (lane >> 4) * 4 + j;
          out[((size_t)b * 50 + t) * 4096 + gc] = acc[m][j] + bias;
        }
      }
      __syncthreads();  // protect s_h before next t's staging
    }
  }
}

// ============================================================================
// Stage 4 (fallback): one LSTM step per launch (hang-proof). Used only if the
// cooperative launch is rejected; head GEMM then runs as separate dispatch.
// ============================================================================
__global__ __launch_bounds__(256) void k_lstm_step1(
    const float* __restrict__ xgT, const float* __restrict__ w_hh,
    const float* __restrict__ hin, float* __restrict__ hout,
    unsigned short* __restrict__ hallf_t, float* __restrict__ cbuf, int t)
{
  __shared__ float s_w[8][512];
  __shared__ float s_g[2][4][64];
  const int tid = threadIdx.x;
  const int dd0 = blockIdx.x * 2;

  for (int idx = tid; idx < 1024; idx += 256) {
    int row = idx >> 7;
    int k4 = (idx & 127) << 2;
    int q_ = row >> 1, dd_i = row & 1;
    *(float4*)&s_w[row][k4] =
        *(const float4*)(w_hh + (size_t)(q_ * 512 + dd0 + dd_i) * 512 + k4);
  }
  const int b = tid & 63;
  const int q = tid >> 6;
  __syncthreads();

  const float* hc = hin + b * 512;
  const float* xr = xgT + (size_t)t * 131072 + (size_t)(q * 512 + dd0) * 64 + b;
  float a0 = xr[0], a1 = xr[64];
  const float* w0 = s_w[q * 2 + 0];
  const float* w1 = s_w[q * 2 + 1];
#pragma unroll 8
  for (int k = 0; k < 512; k += 4) {
    float4 h4 = *(const float4*)(hc + k);
    float4 u = *(const float4*)(w0 + k);
    float4 v = *(const float4*)(w1 + k);
    a0 = fmaf(h4.x, u.x, fmaf(h4.y, u.y, fmaf(h4.z, u.z, fmaf(h4.w, u.w, a0))));
    a1 = fmaf(h4.x, v.x, fmaf(h4.y, v.y, fmaf(h4.z, v.z, fmaf(h4.w, v.w, a1))));
  }
  s_g[0][q][b] = a0;
  s_g[1][q][b] = a1;
  __syncthreads();
  if (q < 2) {
    const int dd = dd0 + q;
    float gi = s_g[q][0][b], gf = s_g[q][1][b];
    float gg = s_g[q][2][b], go = s_g[q][3][b];
    float ig = 1.f / (1.f + expf(-gi));
    float fg = 1.f / (1.f + expf(-gf));
    float og = 1.f / (1.f + expf(-go));
    float gt = tanhf(gg);
    float c = fmaf(fg, cbuf[b * 512 + dd], ig * gt);
    float h = og * tanhf(c);
    cbuf[b * 512 + dd] = c;
    hout[b * 512 + dd] = h;
    hallf_t[(size_t)b * 512 + dd] = f2h(h);
  }
}

// ============================================================================
extern "C" void kernel_launch(void* const* d_in, const int* in_sizes, int n_in,
                              void* d_out, int out_size, void* d_ws,
                              size_t ws_size, hipStream_t stream) {
  const float* mask   = (const float*)d_in[0];
  const int*   tgt    = (const int*)d_in[1];
  const float* w1     = (const float*)d_in[2];
  const float* b1     = (const float*)d_in[3];
  const float* w2     = (const float*)d_in[4];
  const float* b2     = (const float*)d_in[5];
  const float* feat_w = (const float*)d_in[6];
  const float* feat_b = (const float*)d_in[7];
  const float* ctx_w  = (const float*)d_in[8];
  const float* ctx_b  = (const float*)d_in[9];
  const float* temb   = (const float*)d_in[10];
  const float* w_ih   = (const float*)d_in[11];
  const float* w_hh_p = (const float*)d_in[12];
  const float* b_ih   = (const float*)d_in[13];
  const float* b_hh   = (const float*)d_in[14];
  const float* head_w = (const float*)d_in[15];
  const float* head_b = (const float*)d_in[16];

  float* ws = (float*)d_ws;
  // float-unit offsets; total 9,127,488 floats = 36.5 MB (< proven 39.85 MB)
  float* part  = ws;                       // [0, 65536)
  float* hbuf  = ws + 65536;               // [65536, 131072)  fp32 (fallback)
  float* ctx   = ws + 131072;              // [131072, 163840)
  int*   flags = (int*)(ws + 163840);      // [163840, 165440) 1600 ints
  unsigned short* h0f  = (unsigned short*)(ws + 165440);    // 16384 fl
  unsigned short* Ab16 = (unsigned short*)(ws + 181824);    // 819200 fl
  unsigned short* hallf = Ab16;            // overlay: Ab16 dead after gemm<0>
  unsigned short* wihb = (unsigned short*)(ws + 1001024);   // 524288 fl
  unsigned short* hwb  = (unsigned short*)(ws + 1525312);   // 1048576 fl
  float* xgT   = ws + 2573888;             // 6553600 fl, ends 9127488
  float* cbuf  = part;                     // overlay: part dead after pool_h0
  float* out   = (float*)d_out;            // (64,50,4096)

  k_conv<<<2048, 512, 0, stream>>>(mask, w1, b1, w2, b2, part);
  k_f2h<<<1024, 256, 0, stream>>>(w_ih, wihb, 1048576);
  k_f2h<<<2048, 256, 0, stream>>>(head_w, hwb, 2097152);
  k_zero_i<<<7, 256, 0, stream>>>(flags, 1600);
  k_pool_h0<<<64, 256, 0, stream>>>(part, feat_w, feat_b, hbuf, h0f);
  k_ctx<<<64, 256, 0, stream>>>(hbuf, ctx_w, ctx_b, ctx);
  k_build_A<<<3200, 128, 0, stream>>>(temb, tgt, ctx, Ab16);
  k_gemm_mfma<0><<<25 * 16, 256, 0, stream>>>(Ab16, wihb, b_ih, b_hh, xgT, 16);

  // Persistent LSTM + fused head GEMM (cooperative -> co-residency guaranteed).
  {
    const float* xgT_c = xgT;
    const float* whh_c = w_hh_p;
    const unsigned short* h0f_c = h0f;
    unsigned short* hallf_c = hallf;
    const unsigned short* hwb_c = hwb;
    const float* headb_c = head_b;
    float* out_c = out;
    int* flags_c = flags;
    void* args[] = {(void*)&xgT_c,  (void*)&whh_c,   (void*)&h0f_c,
                    (void*)&hallf_c, (void*)&hwb_c,  (void*)&headb_c,
                    (void*)&out_c,   (void*)&flags_c};
    hipError_t e = hipLaunchCooperativeKernel(
        (const void*)k_lstm_head, dim3(REC_NB + HEAD_NB), dim3(256), args, 0,
        stream);
    if (e != hipSuccess) {
      (void)hipGetLastError();  // clear sticky error
      k_zero_f<<<128, 256, 0, stream>>>(cbuf);
      for (int t = 0; t < 50; t++) {
        const float* hin = hbuf + (t & 1) * 32768;
        float* hout = hbuf + ((t + 1) & 1) * 32768;
        k_lstm_step1<<<256, 256, 0, stream>>>(
            xgT, w_hh_p, hin, hout, hallf + (size_t)t * 32768, cbuf, t);
      }
      k_gemm_mfma<1><<<25 * 32, 256, 0, stream>>>(hallf, hwb, head_b, nullptr,
                                                  out, 32);
    }
  }
}

// Round 10
// 545.164 us; speedup vs baseline: 1.1323x; 1.1323x over previous
//
#include <hip/hip_runtime.h>
#include <cmath>

typedef __attribute__((ext_vector_type(8))) _Float16 f16x8;
typedef __attribute__((ext_vector_type(4))) float f32x4;
typedef __attribute__((ext_vector_type(4))) unsigned u32x4;

#define LSTM_NB 32

__device__ __forceinline__ unsigned short f2h(float x) {
  return __builtin_bit_cast(unsigned short, (_Float16)x);
}

__device__ __forceinline__ void h2f2(unsigned u, float& a, float& b) {
  a = (float)__builtin_bit_cast(_Float16, (unsigned short)(u & 0xffffu));
  b = (float)__builtin_bit_cast(_Float16, (unsigned short)(u >> 16));
}

__device__ __forceinline__ void gload16(const void* g, void* l) {
  __builtin_amdgcn_global_load_lds(
      (const __attribute__((address_space(1))) void*)g,
      (__attribute__((address_space(3))) void*)l, 16, 0, 0);
}

// Coherent (cache-bypassing) coalesced 16B load — round-7-proven mechanism
// for reading same-dispatch agent-atomic stores.
__device__ __forceinline__ void cload16(const void* p, u32x4* dst) {
  asm volatile("global_load_dwordx4 %0, %1, off sc0 sc1"
               : "=v"(*dst)
               : "v"(p));
}

// ============================================================================
// Stage 1: fused conv1 + relu + maxpool2x2 + conv2 + relu + spatial-sum.
// Round-10: conv1+pool tile stored as f16 in LDS (41.5 -> 20.7 KB; block
// total ~40 KB) and p-rows read as packed dwords (half the LDS ops). fp32
// math unchanged; f16 storage error ~5e-4 rel on O(1) activations.
// ============================================================================
__global__ __launch_bounds__(512) void k_conv(
    const float* __restrict__ mask, const float* __restrict__ w1,
    const float* __restrict__ b1, const float* __restrict__ w2,
    const float* __restrict__ b2, float* __restrict__ part)
{
  __shared__ unsigned short s_p1[16][18 * 36];  // f16 storage
  __shared__ float s_w1[144];
  __shared__ float s_b1[16];
  __shared__ float s_w2[4608];
  __shared__ float s_b2[32];

  const int tid = threadIdx.x;
  const int b = blockIdx.x >> 5;
  const int tile = blockIdx.x & 31;
  const int px0 = (tile & 3) * 32, py0 = (tile >> 2) * 16;
  const float* mb = mask + (size_t)b * 65536;

  for (int i = tid; i < 144; i += 512) s_w1[i] = w1[i];
  for (int i = tid; i < 4608; i += 512) s_w2[i] = w2[i];
  if (tid < 16) s_b1[tid] = b1[tid];
  if (tid < 32) s_b2[tid] = b2[tid];
  __syncthreads();

  for (int idx = tid; idx < 18 * 34; idx += 512) {
    int ly = idx / 34, lx = idx - ly * 34;
    int py = py0 - 1 + ly, px = px0 - 1 + lx;
    if (py < 0 || py >= 128 || px < 0 || px >= 128) {
      for (int o = 0; o < 16; o++) s_p1[o][ly * 36 + lx] = 0;
    } else {
      float patch[4][4];
      int gy0 = 2 * py - 1, gx0 = 2 * px - 1;
#pragma unroll
      for (int i = 0; i < 4; i++) {
        int gy = gy0 + i;
        bool yok = (gy >= 0 && gy < 256);
#pragma unroll
        for (int j = 0; j < 4; j++) {
          int gx = gx0 + j;
          patch[i][j] = (yok && gx >= 0 && gx < 256) ? mb[gy * 256 + gx] : 0.f;
        }
      }
      for (int o = 0; o < 16; o++) {
        float m = 0.f;
#pragma unroll
        for (int dy = 0; dy < 2; dy++)
#pragma unroll
          for (int dx = 0; dx < 2; dx++) {
            float v = s_b1[o];
#pragma unroll
            for (int ky = 0; ky < 3; ky++)
#pragma unroll
              for (int kx = 0; kx < 3; kx++)
                v = fmaf(patch[dy + ky][dx + kx], s_w1[o * 9 + ky * 3 + kx], v);
            m = fmaxf(m, v);
          }
        s_p1[o][ly * 36 + lx] = f2h(m);
      }
    }
  }
  __syncthreads();

  const int ocg = tid >> 6;
  const int sp = tid & 63;
  const int sx = (sp & 7) * 4, sy = (sp >> 3) * 2;
  float acc[4][8];
#pragma unroll
  for (int a = 0; a < 4; a++)
#pragma unroll
    for (int q = 0; q < 8; q++) acc[a][q] = 0.f;

  for (int ic = 0; ic < 16; ic++) {
    float p[4][6];
#pragma unroll
    for (int i = 0; i < 4; i++) {
      const unsigned short* row = &s_p1[ic][(sy + i) * 36 + sx];
      unsigned u0 = *(const unsigned*)(row);
      unsigned u1 = *(const unsigned*)(row + 2);
      unsigned u2 = *(const unsigned*)(row + 4);
      h2f2(u0, p[i][0], p[i][1]);
      h2f2(u1, p[i][2], p[i][3]);
      h2f2(u2, p[i][4], p[i][5]);
    }
#pragma unroll
    for (int o4 = 0; o4 < 4; o4++) {
      const int oc = ocg * 4 + o4;
      const float* w = &s_w2[(oc * 16 + ic) * 9];
      float w00 = w[0], w01 = w[1], w02 = w[2];
      float w10 = w[3], w11 = w[4], w12 = w[5];
      float w20 = w[6], w21 = w[7], w22 = w[8];
#pragma unroll
      for (int y = 0; y < 2; y++)
#pragma unroll
        for (int x = 0; x < 4; x++) {
          float s = acc[o4][y * 4 + x];
          s = fmaf(p[y][x], w00, s);
          s = fmaf(p[y][x + 1], w01, s);
          s = fmaf(p[y][x + 2], w02, s);
          s = fmaf(p[y + 1][x], w10, s);
          s = fmaf(p[y + 1][x + 1], w11, s);
          s = fmaf(p[y + 1][x + 2], w12, s);
          s = fmaf(p[y + 2][x], w20, s);
          s = fmaf(p[y + 2][x + 1], w21, s);
          s = fmaf(p[y + 2][x + 2], w22, s);
          acc[o4][y * 4 + x] = s;
        }
    }
  }

  const int lane = tid & 63;
#pragma unroll
  for (int o4 = 0; o4 < 4; o4++) {
    float bv = s_b2[ocg * 4 + o4];
    float s = 0.f;
#pragma unroll
    for (int q = 0; q < 8; q++) s += fmaxf(acc[o4][q] + bv, 0.f);
    for (int off = 32; off > 0; off >>= 1) s += __shfl_down(s, off, 64);
    if (lane == 0) part[(b * 32 + tile) * 32 + ocg * 4 + o4] = s;
  }
}

// ============================================================================
// Stage 2 (fused): tile partials -> pooled mean -> h0 (fp32 + f16) -> ctx.
// One block per batch element; h0 kept in LDS for the ctx GEMV.
// ============================================================================
__global__ __launch_bounds__(256) void k_pool_ctx(
    const float* __restrict__ part, const float* __restrict__ feat_w,
    const float* __restrict__ feat_b, const float* __restrict__ ctx_w,
    const float* __restrict__ ctx_b, float* __restrict__ h0,
    unsigned short* __restrict__ h0f, float* __restrict__ ctx)
{
  const int b = blockIdx.x, tid = threadIdx.x;
  __shared__ float pl[32];
  __shared__ float hs[512];
  if (tid < 32) {
    float s = 0.f;
    for (int t = 0; t < 32; t++) s += part[(b * 32 + t) * 32 + tid];
    pl[tid] = s * (1.0f / 16384.0f);
  }
  __syncthreads();
  for (int j = tid; j < 512; j += 256) {
    float acc = feat_b[j];
    const float* w = feat_w + j * 32;
#pragma unroll
    for (int ic = 0; ic < 32; ic++) acc = fmaf(pl[ic], w[ic], acc);
    h0[b * 512 + j] = acc;
    h0f[b * 512 + j] = f2h(acc);
    hs[j] = acc;
  }
  __syncthreads();
  for (int j = tid; j < 512; j += 256) {
    const float* w = ctx_w + (size_t)j * 512;
    float s0 = 0.f, s1 = 0.f, s2 = 0.f, s3 = 0.f;
    for (int k = 0; k < 512; k += 4) {
      float4 w4 = *(const float4*)(w + k);
      s0 = fmaf(hs[k], w4.x, s0);
      s1 = fmaf(hs[k + 1], w4.y, s1);
      s2 = fmaf(hs[k + 2], w4.z, s2);
      s3 = fmaf(hs[k + 3], w4.w, s3);
    }
    ctx[b * 512 + j] = ctx_b[j] + ((s0 + s1) + (s2 + s3));
  }
}

// ============================================================================
// Prep (fused): f16-convert w_ih (262144 quads) + head_w (524288 quads) and
// zero the barrier counters. Grid 3072 x 256.
// ============================================================================
__global__ __launch_bounds__(256) void k_prep(
    const float* __restrict__ wih, const float* __restrict__ hw,
    unsigned short* __restrict__ wihb, unsigned short* __restrict__ hwb,
    int* __restrict__ cnt)
{
  const int i = blockIdx.x * 256 + threadIdx.x;
  if (i < 64) cnt[i] = 0;
  if (i < 262144) {
    float4 v = *(const float4*)(wih + (size_t)i * 4);
    unsigned lo = (unsigned)f2h(v.x) | ((unsigned)f2h(v.y) << 16);
    unsigned hi = (unsigned)f2h(v.z) | ((unsigned)f2h(v.w) << 16);
    *(uint2*)(wihb + (size_t)i * 4) = make_uint2(lo, hi);
  } else if (i < 786432) {
    const int j = i - 262144;
    float4 v = *(const float4*)(hw + (size_t)j * 4);
    unsigned lo = (unsigned)f2h(v.x) | ((unsigned)f2h(v.y) << 16);
    unsigned hi = (unsigned)f2h(v.z) | ((unsigned)f2h(v.w) << 16);
    *(uint2*)(hwb + (size_t)j * 4) = make_uint2(lo, hi);
  }
}

__global__ __launch_bounds__(256) void k_zero_f(float* __restrict__ p) {
  p[blockIdx.x * 256 + threadIdx.x] = 0.f;
}

// ============================================================================
// Stage 3a: A[(t*64+b)][k] = f16(tok_emb[tok][k] + ctx[b][k])
// ============================================================================
__global__ __launch_bounds__(128) void k_build_A(
    const float* __restrict__ tok_emb, const int* __restrict__ tgt,
    const float* __restrict__ ctx, unsigned short* __restrict__ A)
{
  const int r = blockIdx.x;
  const int t = r >> 6, b = r & 63;
  const int tok = (t == 0) ? 4096 : tgt[b * 50 + (t - 1)];
  const int i = threadIdx.x * 4;
  float4 ev = *(const float4*)(tok_emb + (size_t)tok * 512 + i);
  float4 cv = *(const float4*)(ctx + b * 512 + i);
  unsigned lo = (unsigned)f2h(ev.x + cv.x) | ((unsigned)f2h(ev.y + cv.y) << 16);
  unsigned hi = (unsigned)f2h(ev.z + cv.z) | ((unsigned)f2h(ev.w + cv.w) << 16);
  *(uint2*)(A + (size_t)r * 512 + i) = make_uint2(lo, hi);
}

// ============================================================================
// f16 MFMA GEMM (m97 structure): C(MxN) = A(Mx512) @ B(Nx512)^T + bias.
// MODE 0: xgates; C TRANSPOSED (t, gate-dd, b) = (50,2048,64).
// MODE 1: head; C remapped (t*64+b, v) -> (b*50+t, v).
// ============================================================================
template <int MODE>
__global__ __launch_bounds__(256) void k_gemm_mfma(
    const unsigned short* __restrict__ A, const unsigned short* __restrict__ B,
    const float* __restrict__ bias_a, const float* __restrict__ bias_b,
    float* __restrict__ C, int NB)
{
  __shared__ unsigned short sA[128 * 32];
  __shared__ unsigned short sB[128 * 32];
  const int tid = threadIdx.x;
  const int bx = blockIdx.x % NB, by = blockIdx.x / NB;
  const int lane = tid & 63, wv = tid >> 6;
  const int wr = wv >> 1, wc = wv & 1;
  const unsigned short* Ab = A + (size_t)by * 128 * 512;
  const unsigned short* Bb = B + (size_t)bx * 128 * 512;

  f32x4 acc[4][4];
#pragma unroll
  for (int m = 0; m < 4; m++)
#pragma unroll
    for (int n = 0; n < 4; n++) acc[m][n] = (f32x4){0.f, 0.f, 0.f, 0.f};

  const int r0 = tid >> 2, c0 = (tid & 3) * 8;
  const int idx1 = tid + 256;
  const int r1 = idx1 >> 2, c1 = (idx1 & 3) * 8;
  unsigned short* lA0 = sA + (size_t)wv * 512;
  unsigned short* lA1 = sA + 2048 + (size_t)wv * 512;
  unsigned short* lB0 = sB + (size_t)wv * 512;
  unsigned short* lB1 = sB + 2048 + (size_t)wv * 512;

  const int frow = lane & 15;
  const int foff = (lane >> 4) * 8;

  for (int kc = 0; kc < 512; kc += 32) {
    gload16(Ab + (size_t)r0 * 512 + kc + c0, lA0);
    gload16(Ab + (size_t)r1 * 512 + kc + c1, lA1);
    gload16(Bb + (size_t)r0 * 512 + kc + c0, lB0);
    gload16(Bb + (size_t)r1 * 512 + kc + c1, lB1);
    __syncthreads();

    f16x8 af[4], bfr[4];
#pragma unroll
    for (int m = 0; m < 4; m++)
      af[m] = *(const f16x8*)(sA + (wr * 64 + m * 16 + frow) * 32 + foff);
#pragma unroll
    for (int n = 0; n < 4; n++)
      bfr[n] = *(const f16x8*)(sB + (wc * 64 + n * 16 + frow) * 32 + foff);
#pragma unroll
    for (int m = 0; m < 4; m++)
#pragma unroll
      for (int n = 0; n < 4; n++)
        acc[m][n] = __builtin_amdgcn_mfma_f32_16x16x32_f16(
            af[m], bfr[n], acc[m][n], 0, 0, 0);
    __syncthreads();
  }

  // C/D layout (m91-verified, dtype-independent): col=lane&15, row=(lane>>4)*4+j
#pragma unroll
  for (int n = 0; n < 4; n++) {
    const int gc = bx * 128 + wc * 64 + n * 16 + (lane & 15);
    const float bv = (MODE == 0) ? (bias_a[gc] + bias_b[gc]) : bias_a[gc];
#pragma unroll
    for (int m = 0; m < 4; m++) {
      const int rb = by * 128 + wr * 64 + m * 16 + (lane >> 4) * 4;
#pragma unroll
      for (int j = 0; j < 4; j++) {
        const int r = rb + j;
        float v = acc[m][n][j] + bv;
        int t = r >> 6, bb = r & 63;
        if (MODE == 0) {
          C[(size_t)t * 131072 + (size_t)gc * 64 + bb] = v;
        } else {
          C[((size_t)bb * 50 + t) * 4096 + gc] = v;
        }
      }
    }
  }
}

// ============================================================================
// Stage 4 (primary): PERSISTENT MFMA LSTM, one cooperative dispatch, 32 blocks.
// Round-8-proven structure (263 us), byte-identical: f16 datapath, coalesced
// coherent staging + XOR-swizzled LDS, relaxed agent-atomic h stores, counter
// barrier, no fences. (Round-9's in-kernel head fusion regressed the serial
// critical path via coherence-fabric contention — reverted.)
// ============================================================================
__global__ __launch_bounds__(256, 1) void k_lstm_mfma(
    const float* __restrict__ xgT,            // (50,2048,64) xgates (biased)
    const float* __restrict__ w_hh,           // (2048,512) fp32
    const unsigned short* __restrict__ h0f,   // (64,512) f16
    unsigned short* __restrict__ hallf,       // (50,64,512) f16 h history
    int* __restrict__ cnt)                    // >= 50 ints, zeroed
{
  __shared__ unsigned short s_h[64 * 512];    // 64 KB, XOR-swizzled rows
  __shared__ float s_g[4][64][17];            // [gate][batch][dd_rel], 17.4 KB
  const int tid = threadIdx.x;
  const int kb = blockIdx.x;        // dims [16*kb, 16*kb+16)
  const int g = tid >> 6;           // gate = wave
  const int lane = tid & 63;
  const int frow = lane & 15;
  const int foff = (lane >> 4) * 8;

  // Load weight fragments once (f16): 16 frags = 64 VGPRs.
  f16x8 wf[16];
  {
    const float* wrow = w_hh + (size_t)(g * 512 + kb * 16 + frow) * 512;
#pragma unroll
    for (int kf = 0; kf < 16; kf++) {
      float tmp[8];
      *(float4*)tmp = *(const float4*)(wrow + kf * 32 + foff);
      *(float4*)(tmp + 4) = *(const float4*)(wrow + kf * 32 + foff + 4);
#pragma unroll
      for (int j = 0; j < 8; j++) wf[kf][j] = (_Float16)tmp[j];
    }
  }

  float c[4] = {0.f, 0.f, 0.f, 0.f};  // cell state: (dd = kb*16+dd2*4+i, b2)
  const int b2 = tid & 63, dd2 = tid >> 6;

  for (int t = 0; t < 50; ++t) {
    const unsigned short* H = t ? hallf + (size_t)(t - 1) * 32768 : h0f;

    // Prefetch this step's xgates (independent of h) — latency hides under
    // the staging wait.
    const float* xr =
        xgT + (size_t)t * 131072 + (size_t)(kb * 16 + dd2 * 4) * 64 + b2;
    float xv[16];
#pragma unroll
    for (int gq = 0; gq < 4; gq++)
#pragma unroll
      for (int i = 0; i < 4; i++)
        xv[gq * 4 + i] = xr[(size_t)(gq * 512 + i) * 64];

    // ---- Stage H -> LDS: 16 coalesced coherent 16B loads, one vmcnt round.
    {
      u32x4 r[16];
#pragma unroll
      for (int i = 0; i < 16; i++)
        cload16((const char*)H + (size_t)(tid + i * 256) * 16, &r[i]);
      asm volatile("s_waitcnt vmcnt(0)" ::: "memory");
      __builtin_amdgcn_sched_barrier(0);
#pragma unroll
      for (int i = 0; i < 16; i++) {
        int byte = (tid + i * 256) * 16;
        int swz = byte ^ (((byte >> 10) & 7) << 4);
        *(u32x4*)((char*)s_h + swz) = r[i];
      }
    }
    __syncthreads();

    // ---- MFMA from LDS (XOR-swizzled fragment reads), 64 MFMAs/wave.
    f32x4 acc[4];
#pragma unroll
    for (int mt = 0; mt < 4; mt++) acc[mt] = (f32x4){0.f, 0.f, 0.f, 0.f};
#pragma unroll
    for (int kf = 0; kf < 16; kf++) {
#pragma unroll
      for (int mt = 0; mt < 4; mt++) {
        const int row = mt * 16 + frow;
        const int byte = (row << 10) + kf * 64 + foff * 2;
        const int swz = byte ^ ((row & 7) << 4);
        f16x8 ah = *(const f16x8*)((const char*)s_h + swz);
        acc[mt] =
            __builtin_amdgcn_mfma_f32_16x16x32_f16(ah, wf[kf], acc[mt], 0, 0, 0);
      }
    }
    // C/D: col = lane&15 (dd_rel), row = (lane>>4)*4 + j (batch)
#pragma unroll
    for (int mt = 0; mt < 4; mt++)
#pragma unroll
      for (int j = 0; j < 4; j++)
        s_g[g][mt * 16 + (lane >> 4) * 4 + j][frow] = acc[mt][j];
    __syncthreads();

    // ---- c/h update: thread owns 4 cells (dd = kb*16 + dd2*4 + i, batch b2).
    unsigned long long qf = 0;
#pragma unroll
    for (int i = 0; i < 4; i++) {
      float gi = s_g[0][b2][dd2 * 4 + i] + xv[0 + i];
      float gf = s_g[1][b2][dd2 * 4 + i] + xv[4 + i];
      float gg = s_g[2][b2][dd2 * 4 + i] + xv[8 + i];
      float go = s_g[3][b2][dd2 * 4 + i] + xv[12 + i];
      float ig = 1.f / (1.f + expf(-gi));
      float fg = 1.f / (1.f + expf(-gf));
      float og = 1.f / (1.f + expf(-go));
      float gt = tanhf(gg);
      c[i] = fmaf(fg, c[i], ig * gt);
      float h = og * tanhf(c[i]);
      qf |= (unsigned long long)f2h(h) << (16 * i);
    }
    const size_t ho = (size_t)b2 * 512 + kb * 16 + dd2 * 4;
    __hip_atomic_store((unsigned long long*)(hallf + (size_t)t * 32768 + ho),
                       qf, __ATOMIC_RELAXED, __HIP_MEMORY_SCOPE_AGENT);
    __syncthreads();  // drains vmcnt(0) on every wave -> stores visible
    if (tid == 0) {
      __hip_atomic_fetch_add(&cnt[t], 1, __ATOMIC_RELAXED,
                             __HIP_MEMORY_SCOPE_AGENT);
      while (__hip_atomic_load(&cnt[t], __ATOMIC_RELAXED,
                               __HIP_MEMORY_SCOPE_AGENT) < LSTM_NB) {
        __builtin_amdgcn_s_sleep(1);
      }
    }
    __syncthreads();
  }
}

// ============================================================================
// Stage 4 (fallback): one LSTM step per launch (hang-proof). Used only if the
// cooperative launch is rejected.
// ============================================================================
__global__ __launch_bounds__(256) void k_lstm_step1(
    const float* __restrict__ xgT, const float* __restrict__ w_hh,
    const float* __restrict__ hin, float* __restrict__ hout,
    unsigned short* __restrict__ hallf_t, float* __restrict__ cbuf, int t)
{
  __shared__ float s_w[8][512];
  __shared__ float s_g[2][4][64];
  const int tid = threadIdx.x;
  const int dd0 = blockIdx.x * 2;

  for (int idx = tid; idx < 1024; idx += 256) {
    int row = idx >> 7;
    int k4 = (idx & 127) << 2;
    int q_ = row >> 1, dd_i = row & 1;
    *(float4*)&s_w[row][k4] =
        *(const float4*)(w_hh + (size_t)(q_ * 512 + dd0 + dd_i) * 512 + k4);
  }
  const int b = tid & 63;
  const int q = tid >> 6;
  __syncthreads();

  const float* hc = hin + b * 512;
  const float* xr = xgT + (size_t)t * 131072 + (size_t)(q * 512 + dd0) * 64 + b;
  float a0 = xr[0], a1 = xr[64];
  const float* w0 = s_w[q * 2 + 0];
  const float* w1 = s_w[q * 2 + 1];
#pragma unroll 8
  for (int k = 0; k < 512; k += 4) {
    float4 h4 = *(const float4*)(hc + k);
    float4 u = *(const float4*)(w0 + k);
    float4 v = *(const float4*)(w1 + k);
    a0 = fmaf(h4.x, u.x, fmaf(h4.y, u.y, fmaf(h4.z, u.z, fmaf(h4.w, u.w, a0))));
    a1 = fmaf(h4.x, v.x, fmaf(h4.y, v.y, fmaf(h4.z, v.z, fmaf(h4.w, v.w, a1))));
  }
  s_g[0][q][b] = a0;
  s_g[1][q][b] = a1;
  __syncthreads();
  if (q < 2) {
    const int dd = dd0 + q;
    float gi = s_g[q][0][b], gf = s_g[q][1][b];
    float gg = s_g[q][2][b], go = s_g[q][3][b];
    float ig = 1.f / (1.f + expf(-gi));
    float fg = 1.f / (1.f + expf(-gf));
    float og = 1.f / (1.f + expf(-go));
    float gt = tanhf(gg);
    float c = fmaf(fg, cbuf[b * 512 + dd], ig * gt);
    float h = og * tanhf(c);
    cbuf[b * 512 + dd] = c;
    hout[b * 512 + dd] = h;
    hallf_t[(size_t)b * 512 + dd] = f2h(h);
  }
}

// ============================================================================
extern "C" void kernel_launch(void* const* d_in, const int* in_sizes, int n_in,
                              void* d_out, int out_size, void* d_ws,
                              size_t ws_size, hipStream_t stream) {
  const float* mask   = (const float*)d_in[0];
  const int*   tgt    = (const int*)d_in[1];
  const float* w1     = (const float*)d_in[2];
  const float* b1     = (const float*)d_in[3];
  const float* w2     = (const float*)d_in[4];
  const float* b2     = (const float*)d_in[5];
  const float* feat_w = (const float*)d_in[6];
  const float* feat_b = (const float*)d_in[7];
  const float* ctx_w  = (const float*)d_in[8];
  const float* ctx_b  = (const float*)d_in[9];
  const float* temb   = (const float*)d_in[10];
  const float* w_ih   = (const float*)d_in[11];
  const float* w_hh_p = (const float*)d_in[12];
  const float* b_ih   = (const float*)d_in[13];
  const float* b_hh   = (const float*)d_in[14];
  const float* head_w = (const float*)d_in[15];
  const float* head_b = (const float*)d_in[16];

  float* ws = (float*)d_ws;
  // float-unit offsets; total 9,125,952 floats = 36.5 MB (< proven 39.85 MB)
  float* part  = ws;                       // [0, 65536)
  float* hbuf  = ws + 65536;               // [65536, 131072)  fp32 (fallback)
  float* ctx   = ws + 131072;              // [131072, 163840)
  int*   cnt   = (int*)(ws + 163840);      // [163840, 163904) 64 ints
  unsigned short* h0f  = (unsigned short*)(ws + 163904);    // 16384 fl
  unsigned short* Ab16 = (unsigned short*)(ws + 180288);    // 819200 fl
  unsigned short* hallf = Ab16;            // overlay: Ab16 dead after gemm<0>
  unsigned short* wihb = (unsigned short*)(ws + 999488);    // 524288 fl
  unsigned short* hwb  = (unsigned short*)(ws + 1523776);   // 1048576 fl
  float* xgT   = ws + 2572352;             // 6553600 fl, ends 9125952
  float* cbuf  = part;                     // overlay: part dead after pool_ctx
  float* out   = (float*)d_out;            // (64,50,4096)

  k_conv<<<2048, 512, 0, stream>>>(mask, w1, b1, w2, b2, part);
  k_prep<<<3072, 256, 0, stream>>>(w_ih, head_w, wihb, hwb, cnt);
  k_pool_ctx<<<64, 256, 0, stream>>>(part, feat_w, feat_b, ctx_w, ctx_b,
                                     hbuf, h0f, ctx);
  k_build_A<<<3200, 128, 0, stream>>>(temb, tgt, ctx, Ab16);
  k_gemm_mfma<0><<<25 * 16, 256, 0, stream>>>(Ab16, wihb, b_ih, b_hh, xgT, 16);

  // Persistent MFMA LSTM (cooperative -> co-residency guaranteed, hang-proof).
  {
    const float* xgT_c = xgT;
    const float* whh_c = w_hh_p;
    const unsigned short* h0f_c = h0f;
    unsigned short* hallf_c = hallf;
    int* cnt_c = cnt;
    void* args[] = {(void*)&xgT_c, (void*)&whh_c, (void*)&h0f_c,
                    (void*)&hallf_c, (void*)&cnt_c};
    hipError_t e = hipLaunchCooperativeKernel(
        (const void*)k_lstm_mfma, dim3(LSTM_NB), dim3(256), args, 0, stream);
    if (e != hipSuccess) {
      (void)hipGetLastError();  // clear sticky error
      k_zero_f<<<128, 256, 0, stream>>>(cbuf);
      for (int t = 0; t < 50; t++) {
        const float* hin = hbuf + (t & 1) * 32768;
        float* hout = hbuf + ((t + 1) & 1) * 32768;
        k_lstm_step1<<<256, 256, 0, stream>>>(
            xgT, w_hh_p, hin, hout, hallf + (size_t)t * 32768, cbuf, t);
      }
    }
  }

  k_gemm_mfma<1><<<25 * 32, 256, 0, stream>>>(hallf, hwb, head_b, nullptr, out, 32);
}

// Round 11
// 510.558 us; speedup vs baseline: 1.2090x; 1.0678x over previous
//
#include <hip/hip_runtime.h>
#include <cmath>

typedef __attribute__((ext_vector_type(8))) _Float16 f16x8;
typedef __attribute__((ext_vector_type(2))) _Float16 f16x2;
typedef __attribute__((ext_vector_type(4))) float f32x4;
typedef __attribute__((ext_vector_type(4))) unsigned u32x4;

#define LSTM_NB 32

__device__ __forceinline__ unsigned short f2h(float x) {
  return __builtin_bit_cast(unsigned short, (_Float16)x);
}

__device__ __forceinline__ float dot2(unsigned a, unsigned b, float c) {
#if __has_builtin(__builtin_amdgcn_fdot2)
  return __builtin_amdgcn_fdot2(__builtin_bit_cast(f16x2, a),
                                __builtin_bit_cast(f16x2, b), c, false);
#else
  f16x2 av = __builtin_bit_cast(f16x2, a), bv = __builtin_bit_cast(f16x2, b);
  return fmaf((float)av[0], (float)bv[0], fmaf((float)av[1], (float)bv[1], c));
#endif
}

__device__ __forceinline__ void gload16(const void* g, void* l) {
  __builtin_amdgcn_global_load_lds(
      (const __attribute__((address_space(1))) void*)g,
      (__attribute__((address_space(3))) void*)l, 16, 0, 0);
}

// Coherent (cache-bypassing) coalesced 16B load — round-7-proven mechanism
// for reading same-dispatch agent-atomic stores.
__device__ __forceinline__ void cload16(const void* p, u32x4* dst) {
  asm volatile("global_load_dwordx4 %0, %1, off sc0 sc1"
               : "=v"(*dst)
               : "v"(p));
}

// ============================================================================
// Stage 1: fused conv1 + relu + maxpool2x2 + conv2 + relu + spatial-sum.
// Round-11: conv1+pool tile stored as CHANNEL-PAIR packed f16 (u32), conv2
// weights pre-packed to f16 pairs; inner loop uses v_dot2_f32_f16 (2x FMA
// rate, fp32 accumulate). LDS ~31 KB.
// ============================================================================
__global__ __launch_bounds__(512) void k_conv(
    const float* __restrict__ mask, const float* __restrict__ w1,
    const float* __restrict__ b1, const float* __restrict__ w2,
    const float* __restrict__ b2, float* __restrict__ part)
{
  __shared__ unsigned s_p1p[8][18 * 36];   // [ic pair][pos], 20.7 KB
  __shared__ unsigned s_w2p[32][8][9];     // packed conv2 weights, 9.2 KB
  __shared__ float s_w1[144];
  __shared__ float s_b1[16];
  __shared__ float s_b2[32];

  const int tid = threadIdx.x;
  const int b = blockIdx.x >> 5;
  const int tile = blockIdx.x & 31;
  const int px0 = (tile & 3) * 32, py0 = (tile >> 2) * 16;
  const float* mb = mask + (size_t)b * 65536;

  for (int i = tid; i < 144; i += 512) s_w1[i] = w1[i];
  for (int i = tid; i < 2304; i += 512) {
    int oc = i / 72, p8 = (i % 72) / 9, k = i % 9;
    unsigned lo = f2h(w2[(size_t)(oc * 16 + 2 * p8) * 9 + k]);
    unsigned hi = f2h(w2[(size_t)(oc * 16 + 2 * p8 + 1) * 9 + k]);
    s_w2p[oc][p8][k] = lo | (hi << 16);
  }
  if (tid < 16) s_b1[tid] = b1[tid];
  if (tid < 32) s_b2[tid] = b2[tid];
  __syncthreads();

  // conv1 + relu + 2x2 maxpool -> packed pairs in s_p1p (18x34 incl. halo).
  for (int idx = tid; idx < 18 * 34; idx += 512) {
    int ly = idx / 34, lx = idx - ly * 34;
    int py = py0 - 1 + ly, px = px0 - 1 + lx;
    if (py < 0 || py >= 128 || px < 0 || px >= 128) {
      for (int p8 = 0; p8 < 8; p8++) s_p1p[p8][ly * 36 + lx] = 0;
    } else {
      float patch[4][4];
      int gy0 = 2 * py - 1, gx0 = 2 * px - 1;
#pragma unroll
      for (int i = 0; i < 4; i++) {
        int gy = gy0 + i;
        bool yok = (gy >= 0 && gy < 256);
#pragma unroll
        for (int j = 0; j < 4; j++) {
          int gx = gx0 + j;
          patch[i][j] = (yok && gx >= 0 && gx < 256) ? mb[gy * 256 + gx] : 0.f;
        }
      }
      float m[16];
      for (int o = 0; o < 16; o++) {
        float mm = 0.f;
#pragma unroll
        for (int dy = 0; dy < 2; dy++)
#pragma unroll
          for (int dx = 0; dx < 2; dx++) {
            float v = s_b1[o];
#pragma unroll
            for (int ky = 0; ky < 3; ky++)
#pragma unroll
              for (int kx = 0; kx < 3; kx++)
                v = fmaf(patch[dy + ky][dx + kx], s_w1[o * 9 + ky * 3 + kx], v);
            mm = fmaxf(mm, v);
          }
        m[o] = mm;
      }
#pragma unroll
      for (int p8 = 0; p8 < 8; p8++)
        s_p1p[p8][ly * 36 + lx] =
            (unsigned)f2h(m[2 * p8]) | ((unsigned)f2h(m[2 * p8 + 1]) << 16);
    }
  }
  __syncthreads();

  // conv2 (3x3, 16->32ch) + relu + tile-sum via packed-pair dot2.
  const int ocg = tid >> 6;            // uniform per wave
  const int sp = tid & 63;
  const int sx = (sp & 7) * 4, sy = (sp >> 3) * 2;
  float acc[4][8];
#pragma unroll
  for (int a = 0; a < 4; a++)
#pragma unroll
    for (int q = 0; q < 8; q++) acc[a][q] = 0.f;

  for (int p8 = 0; p8 < 8; p8++) {
    unsigned pp[4][6];
#pragma unroll
    for (int i = 0; i < 4; i++) {
      const unsigned* row = &s_p1p[p8][(sy + i) * 36 + sx];
#pragma unroll
      for (int j = 0; j < 6; j++) pp[i][j] = row[j];
    }
#pragma unroll
    for (int o4 = 0; o4 < 4; o4++) {
      const unsigned* w = &s_w2p[ocg * 4 + o4][p8][0];
      unsigned w00 = w[0], w01 = w[1], w02 = w[2];
      unsigned w10 = w[3], w11 = w[4], w12 = w[5];
      unsigned w20 = w[6], w21 = w[7], w22 = w[8];
#pragma unroll
      for (int y = 0; y < 2; y++)
#pragma unroll
        for (int x = 0; x < 4; x++) {
          float s = acc[o4][y * 4 + x];
          s = dot2(pp[y][x], w00, s);
          s = dot2(pp[y][x + 1], w01, s);
          s = dot2(pp[y][x + 2], w02, s);
          s = dot2(pp[y + 1][x], w10, s);
          s = dot2(pp[y + 1][x + 1], w11, s);
          s = dot2(pp[y + 1][x + 2], w12, s);
          s = dot2(pp[y + 2][x], w20, s);
          s = dot2(pp[y + 2][x + 1], w21, s);
          s = dot2(pp[y + 2][x + 2], w22, s);
          acc[o4][y * 4 + x] = s;
        }
    }
  }

  const int lane = tid & 63;
#pragma unroll
  for (int o4 = 0; o4 < 4; o4++) {
    float bv = s_b2[ocg * 4 + o4];
    float s = 0.f;
#pragma unroll
    for (int q = 0; q < 8; q++) s += fmaxf(acc[o4][q] + bv, 0.f);
    for (int off = 32; off > 0; off >>= 1) s += __shfl_down(s, off, 64);
    if (lane == 0) part[(b * 32 + tile) * 32 + ocg * 4 + o4] = s;
  }
}

// ============================================================================
// Stage 2 (fused): tile partials -> pooled mean -> h0 (fp32 + f16) -> ctx.
// ============================================================================
__global__ __launch_bounds__(256) void k_pool_ctx(
    const float* __restrict__ part, const float* __restrict__ feat_w,
    const float* __restrict__ feat_b, const float* __restrict__ ctx_w,
    const float* __restrict__ ctx_b, float* __restrict__ h0,
    unsigned short* __restrict__ h0f, float* __restrict__ ctx)
{
  const int b = blockIdx.x, tid = threadIdx.x;
  __shared__ float pl[32];
  __shared__ float hs[512];
  if (tid < 32) {
    float s = 0.f;
    for (int t = 0; t < 32; t++) s += part[(b * 32 + t) * 32 + tid];
    pl[tid] = s * (1.0f / 16384.0f);
  }
  __syncthreads();
  for (int j = tid; j < 512; j += 256) {
    float acc = feat_b[j];
    const float* w = feat_w + j * 32;
#pragma unroll
    for (int ic = 0; ic < 32; ic++) acc = fmaf(pl[ic], w[ic], acc);
    h0[b * 512 + j] = acc;
    h0f[b * 512 + j] = f2h(acc);
    hs[j] = acc;
  }
  __syncthreads();
  for (int j = tid; j < 512; j += 256) {
    const float* w = ctx_w + (size_t)j * 512;
    float s0 = 0.f, s1 = 0.f, s2 = 0.f, s3 = 0.f;
    for (int k = 0; k < 512; k += 4) {
      float4 w4 = *(const float4*)(w + k);
      s0 = fmaf(hs[k], w4.x, s0);
      s1 = fmaf(hs[k + 1], w4.y, s1);
      s2 = fmaf(hs[k + 2], w4.z, s2);
      s3 = fmaf(hs[k + 3], w4.w, s3);
    }
    ctx[b * 512 + j] = ctx_b[j] + ((s0 + s1) + (s2 + s3));
  }
}

// ============================================================================
// Prep (fused): f16-convert w_ih + head_w, zero the 1600 barrier flags.
// ============================================================================
__global__ __launch_bounds__(256) void k_prep(
    const float* __restrict__ wih, const float* __restrict__ hw,
    unsigned short* __restrict__ wihb, unsigned short* __restrict__ hwb,
    int* __restrict__ flags)
{
  const int i = blockIdx.x * 256 + threadIdx.x;
  if (i < 1600) flags[i] = 0;
  if (i < 262144) {
    float4 v = *(const float4*)(wih + (size_t)i * 4);
    unsigned lo = (unsigned)f2h(v.x) | ((unsigned)f2h(v.y) << 16);
    unsigned hi = (unsigned)f2h(v.z) | ((unsigned)f2h(v.w) << 16);
    *(uint2*)(wihb + (size_t)i * 4) = make_uint2(lo, hi);
  } else if (i < 786432) {
    const int j = i - 262144;
    float4 v = *(const float4*)(hw + (size_t)j * 4);
    unsigned lo = (unsigned)f2h(v.x) | ((unsigned)f2h(v.y) << 16);
    unsigned hi = (unsigned)f2h(v.z) | ((unsigned)f2h(v.w) << 16);
    *(uint2*)(hwb + (size_t)j * 4) = make_uint2(lo, hi);
  }
}

__global__ __launch_bounds__(256) void k_zero_f(float* __restrict__ p) {
  p[blockIdx.x * 256 + threadIdx.x] = 0.f;
}

// ============================================================================
// Stage 3a: A[(t*64+b)][k] = f16(tok_emb[tok][k] + ctx[b][k])
// ============================================================================
__global__ __launch_bounds__(128) void k_build_A(
    const float* __restrict__ tok_emb, const int* __restrict__ tgt,
    const float* __restrict__ ctx, unsigned short* __restrict__ A)
{
  const int r = blockIdx.x;
  const int t = r >> 6, b = r & 63;
  const int tok = (t == 0) ? 4096 : tgt[b * 50 + (t - 1)];
  const int i = threadIdx.x * 4;
  float4 ev = *(const float4*)(tok_emb + (size_t)tok * 512 + i);
  float4 cv = *(const float4*)(ctx + b * 512 + i);
  unsigned lo = (unsigned)f2h(ev.x + cv.x) | ((unsigned)f2h(ev.y + cv.y) << 16);
  unsigned hi = (unsigned)f2h(ev.z + cv.z) | ((unsigned)f2h(ev.w + cv.w) << 16);
  *(uint2*)(A + (size_t)r * 512 + i) = make_uint2(lo, hi);
}

// ============================================================================
// f16 MFMA GEMM (m97 structure): C(MxN) = A(Mx512) @ B(Nx512)^T + bias.
// MODE 0: xgates; C TRANSPOSED (t, gate-dd, b) = (50,2048,64).
// MODE 1: head; C remapped (t*64+b, v) -> (b*50+t, v).
// ============================================================================
template <int MODE>
__global__ __launch_bounds__(256) void k_gemm_mfma(
    const unsigned short* __restrict__ A, const unsigned short* __restrict__ B,
    const float* __restrict__ bias_a, const float* __restrict__ bias_b,
    float* __restrict__ C, int NB)
{
  __shared__ unsigned short sA[128 * 32];
  __shared__ unsigned short sB[128 * 32];
  const int tid = threadIdx.x;
  const int bx = blockIdx.x % NB, by = blockIdx.x / NB;
  const int lane = tid & 63, wv = tid >> 6;
  const int wr = wv >> 1, wc = wv & 1;
  const unsigned short* Ab = A + (size_t)by * 128 * 512;
  const unsigned short* Bb = B + (size_t)bx * 128 * 512;

  f32x4 acc[4][4];
#pragma unroll
  for (int m = 0; m < 4; m++)
#pragma unroll
    for (int n = 0; n < 4; n++) acc[m][n] = (f32x4){0.f, 0.f, 0.f, 0.f};

  const int r0 = tid >> 2, c0 = (tid & 3) * 8;
  const int idx1 = tid + 256;
  const int r1 = idx1 >> 2, c1 = (idx1 & 3) * 8;
  unsigned short* lA0 = sA + (size_t)wv * 512;
  unsigned short* lA1 = sA + 2048 + (size_t)wv * 512;
  unsigned short* lB0 = sB + (size_t)wv * 512;
  unsigned short* lB1 = sB + 2048 + (size_t)wv * 512;

  const int frow = lane & 15;
  const int foff = (lane >> 4) * 8;

  for (int kc = 0; kc < 512; kc += 32) {
    gload16(Ab + (size_t)r0 * 512 + kc + c0, lA0);
    gload16(Ab + (size_t)r1 * 512 + kc + c1, lA1);
    gload16(Bb + (size_t)r0 * 512 + kc + c0, lB0);
    gload16(Bb + (size_t)r1 * 512 + kc + c1, lB1);
    __syncthreads();

    f16x8 af[4], bfr[4];
#pragma unroll
    for (int m = 0; m < 4; m++)
      af[m] = *(const f16x8*)(sA + (wr * 64 + m * 16 + frow) * 32 + foff);
#pragma unroll
    for (int n = 0; n < 4; n++)
      bfr[n] = *(const f16x8*)(sB + (wc * 64 + n * 16 + frow) * 32 + foff);
#pragma unroll
    for (int m = 0; m < 4; m++)
#pragma unroll
      for (int n = 0; n < 4; n++)
        acc[m][n] = __builtin_amdgcn_mfma_f32_16x16x32_f16(
            af[m], bfr[n], acc[m][n], 0, 0, 0);
    __syncthreads();
  }

  // C/D layout (m91-verified, dtype-independent): col=lane&15, row=(lane>>4)*4+j
#pragma unroll
  for (int n = 0; n < 4; n++) {
    const int gc = bx * 128 + wc * 64 + n * 16 + (lane & 15);
    const float bv = (MODE == 0) ? (bias_a[gc] + bias_b[gc]) : bias_a[gc];
#pragma unroll
    for (int m = 0; m < 4; m++) {
      const int rb = by * 128 + wr * 64 + m * 16 + (lane >> 4) * 4;
#pragma unroll
      for (int j = 0; j < 4; j++) {
        const int r = rb + j;
        float v = acc[m][n][j] + bv;
        int t = r >> 6, bb = r & 63;
        if (MODE == 0) {
          C[(size_t)t * 131072 + (size_t)gc * 64 + bb] = v;
        } else {
          C[((size_t)bb * 50 + t) * 4096 + gc] = v;
        }
      }
    }
  }
}

// ============================================================================
// Stage 4 (primary): PERSISTENT MFMA LSTM, one cooperative dispatch, 32 blocks.
// Round-11: flag-array barrier replaces atomicAdd+poll — each block's tid0
// fire-and-forget stores flags[t*32+kb]; 32 lanes poll the 32 flags in
// parallel at the TOP of the next iteration (after the xv prefetch issues,
// so load latency overlaps the poll). No RMW round-trip on the critical path.
// Rest identical to the round-8-proven structure.
// ============================================================================
__global__ __launch_bounds__(256, 1) void k_lstm_mfma(
    const float* __restrict__ xgT,            // (50,2048,64) xgates (biased)
    const float* __restrict__ w_hh,           // (2048,512) fp32
    const unsigned short* __restrict__ h0f,   // (64,512) f16
    unsigned short* __restrict__ hallf,       // (50,64,512) f16 h history
    int* __restrict__ flags)                  // 50*32 ints, zeroed
{
  __shared__ unsigned short s_h[64 * 512];    // 64 KB, XOR-swizzled rows
  __shared__ float s_g[4][64][17];            // [gate][batch][dd_rel], 17.4 KB
  const int tid = threadIdx.x;
  const int kb = blockIdx.x;        // dims [16*kb, 16*kb+16)
  const int g = tid >> 6;           // gate = wave
  const int lane = tid & 63;
  const int frow = lane & 15;
  const int foff = (lane >> 4) * 8;

  // Load weight fragments once (f16): 16 frags = 64 VGPRs.
  f16x8 wf[16];
  {
    const float* wrow = w_hh + (size_t)(g * 512 + kb * 16 + frow) * 512;
#pragma unroll
    for (int kf = 0; kf < 16; kf++) {
      float tmp[8];
      *(float4*)tmp = *(const float4*)(wrow + kf * 32 + foff);
      *(float4*)(tmp + 4) = *(const float4*)(wrow + kf * 32 + foff + 4);
#pragma unroll
      for (int j = 0; j < 8; j++) wf[kf][j] = (_Float16)tmp[j];
    }
  }

  float c[4] = {0.f, 0.f, 0.f, 0.f};  // cell state: (dd = kb*16+dd2*4+i, b2)
  const int b2 = tid & 63, dd2 = tid >> 6;

  for (int t = 0; t < 50; ++t) {
    const unsigned short* H = t ? hallf + (size_t)(t - 1) * 32768 : h0f;

    // Prefetch this step's xgates (independent of h) — issues before the
    // flag poll so global-load latency overlaps it.
    const float* xr =
        xgT + (size_t)t * 131072 + (size_t)(kb * 16 + dd2 * 4) * 64 + b2;
    float xv[16];
#pragma unroll
    for (int gq = 0; gq < 4; gq++)
#pragma unroll
      for (int i = 0; i < 4; i++)
        xv[gq * 4 + i] = xr[(size_t)(gq * 512 + i) * 64];

    // Wait for all peers' h[t-1] stores (flag array, parallel poll).
    if (t > 0 && tid < 32) {
      while (__hip_atomic_load(&flags[(t - 1) * 32 + tid], __ATOMIC_RELAXED,
                               __HIP_MEMORY_SCOPE_AGENT) == 0) {
        __builtin_amdgcn_s_sleep(1);
      }
    }
    __syncthreads();

    // ---- Stage H -> LDS: 16 coalesced coherent 16B loads, one vmcnt round.
    {
      u32x4 r[16];
#pragma unroll
      for (int i = 0; i < 16; i++)
        cload16((const char*)H + (size_t)(tid + i * 256) * 16, &r[i]);
      asm volatile("s_waitcnt vmcnt(0)" ::: "memory");
      __builtin_amdgcn_sched_barrier(0);
#pragma unroll
      for (int i = 0; i < 16; i++) {
        int byte = (tid + i * 256) * 16;
        int swz = byte ^ (((byte >> 10) & 7) << 4);
        *(u32x4*)((char*)s_h + swz) = r[i];
      }
    }
    __syncthreads();

    // ---- MFMA from LDS (XOR-swizzled fragment reads), 64 MFMAs/wave.
    f32x4 acc[4];
#pragma unroll
    for (int mt = 0; mt < 4; mt++) acc[mt] = (f32x4){0.f, 0.f, 0.f, 0.f};
#pragma unroll
    for (int kf = 0; kf < 16; kf++) {
#pragma unroll
      for (int mt = 0; mt < 4; mt++) {
        const int row = mt * 16 + frow;
        const int byte = (row << 10) + kf * 64 + foff * 2;
        const int swz = byte ^ ((row & 7) << 4);
        f16x8 ah = *(const f16x8*)((const char*)s_h + swz);
        acc[mt] =
            __builtin_amdgcn_mfma_f32_16x16x32_f16(ah, wf[kf], acc[mt], 0, 0, 0);
      }
    }
    // C/D: col = lane&15 (dd_rel), row = (lane>>4)*4 + j (batch)
#pragma unroll
    for (int mt = 0; mt < 4; mt++)
#pragma unroll
      for (int j = 0; j < 4; j++)
        s_g[g][mt * 16 + (lane >> 4) * 4 + j][frow] = acc[mt][j];
    __syncthreads();

    // ---- c/h update: thread owns 4 cells (dd = kb*16 + dd2*4 + i, batch b2).
    unsigned long long qf = 0;
#pragma unroll
    for (int i = 0; i < 4; i++) {
      float gi = s_g[0][b2][dd2 * 4 + i] + xv[0 + i];
      float gf = s_g[1][b2][dd2 * 4 + i] + xv[4 + i];
      float gg = s_g[2][b2][dd2 * 4 + i] + xv[8 + i];
      float go = s_g[3][b2][dd2 * 4 + i] + xv[12 + i];
      float ig = 1.f / (1.f + expf(-gi));
      float fg = 1.f / (1.f + expf(-gf));
      float og = 1.f / (1.f + expf(-go));
      float gt = tanhf(gg);
      c[i] = fmaf(fg, c[i], ig * gt);
      float h = og * tanhf(c[i]);
      qf |= (unsigned long long)f2h(h) << (16 * i);
    }
    const size_t ho = (size_t)b2 * 512 + kb * 16 + dd2 * 4;
    __hip_atomic_store((unsigned long long*)(hallf + (size_t)t * 32768 + ho),
                       qf, __ATOMIC_RELAXED, __HIP_MEMORY_SCOPE_AGENT);
    __syncthreads();  // drains vmcnt(0) on every wave -> stores visible
    if (t < 49 && tid == 0)
      __hip_atomic_store(&flags[t * 32 + kb], 1, __ATOMIC_RELAXED,
                         __HIP_MEMORY_SCOPE_AGENT);
  }
}

// ============================================================================
// Stage 4 (fallback): one LSTM step per launch (hang-proof). Used only if the
// cooperative launch is rejected.
// ============================================================================
__global__ __launch_bounds__(256) void k_lstm_step1(
    const float* __restrict__ xgT, const float* __restrict__ w_hh,
    const float* __restrict__ hin, float* __restrict__ hout,
    unsigned short* __restrict__ hallf_t, float* __restrict__ cbuf, int t)
{
  __shared__ float s_w[8][512];
  __shared__ float s_g[2][4][64];
  const int tid = threadIdx.x;
  const int dd0 = blockIdx.x * 2;

  for (int idx = tid; idx < 1024; idx += 256) {
    int row = idx >> 7;
    int k4 = (idx & 127) << 2;
    int q_ = row >> 1, dd_i = row & 1;
    *(float4*)&s_w[row][k4] =
        *(const float4*)(w_hh + (size_t)(q_ * 512 + dd0 + dd_i) * 512 + k4);
  }
  const int b = tid & 63;
  const int q = tid >> 6;
  __syncthreads();

  const float* hc = hin + b * 512;
  const float* xr = xgT + (size_t)t * 131072 + (size_t)(q * 512 + dd0) * 64 + b;
  float a0 = xr[0], a1 = xr[64];
  const float* w0 = s_w[q * 2 + 0];
  const float* w1 = s_w[q * 2 + 1];
#pragma unroll 8
  for (int k = 0; k < 512; k += 4) {
    float4 h4 = *(const float4*)(hc + k);
    float4 u = *(const float4*)(w0 + k);
    float4 v = *(const float4*)(w1 + k);
    a0 = fmaf(h4.x, u.x, fmaf(h4.y, u.y, fmaf(h4.z, u.z, fmaf(h4.w, u.w, a0))));
    a1 = fmaf(h4.x, v.x, fmaf(h4.y, v.y, fmaf(h4.z, v.z, fmaf(h4.w, v.w, a1))));
  }
  s_g[0][q][b] = a0;
  s_g[1][q][b] = a1;
  __syncthreads();
  if (q < 2) {
    const int dd = dd0 + q;
    float gi = s_g[q][0][b], gf = s_g[q][1][b];
    float gg = s_g[q][2][b], go = s_g[q][3][b];
    float ig = 1.f / (1.f + expf(-gi));
    float fg = 1.f / (1.f + expf(-gf));
    float og = 1.f / (1.f + expf(-go));
    float gt = tanhf(gg);
    float c = fmaf(fg, cbuf[b * 512 + dd], ig * gt);
    float h = og * tanhf(c);
    cbuf[b * 512 + dd] = c;
    hout[b * 512 + dd] = h;
    hallf_t[(size_t)b * 512 + dd] = f2h(h);
  }
}

// ============================================================================
extern "C" void kernel_launch(void* const* d_in, const int* in_sizes, int n_in,
                              void* d_out, int out_size, void* d_ws,
                              size_t ws_size, hipStream_t stream) {
  const float* mask   = (const float*)d_in[0];
  const int*   tgt    = (const int*)d_in[1];
  const float* w1     = (const float*)d_in[2];
  const float* b1     = (const float*)d_in[3];
  const float* w2     = (const float*)d_in[4];
  const float* b2     = (const float*)d_in[5];
  const float* feat_w = (const float*)d_in[6];
  const float* feat_b = (const float*)d_in[7];
  const float* ctx_w  = (const float*)d_in[8];
  const float* ctx_b  = (const float*)d_in[9];
  const float* temb   = (const float*)d_in[10];
  const float* w_ih   = (const float*)d_in[11];
  const float* w_hh_p = (const float*)d_in[12];
  const float* b_ih   = (const float*)d_in[13];
  const float* b_hh   = (const float*)d_in[14];
  const float* head_w = (const float*)d_in[15];
  const float* head_b = (const float*)d_in[16];

  float* ws = (float*)d_ws;
  // float-unit offsets; total 9,127,488 floats = 36.5 MB (< proven 39.85 MB)
  float* part  = ws;                       // [0, 65536)
  float* hbuf  = ws + 65536;               // [65536, 131072)  fp32 (fallback)
  float* ctx   = ws + 131072;              // [131072, 163840)
  int*   flags = (int*)(ws + 163840);      // [163840, 165440) 1600 ints
  unsigned short* h0f  = (unsigned short*)(ws + 165440);    // 16384 fl
  unsigned short* Ab16 = (unsigned short*)(ws + 181824);    // 819200 fl
  unsigned short* hallf = Ab16;            // overlay: Ab16 dead after gemm<0>
  unsigned short* wihb = (unsigned short*)(ws + 1001024);   // 524288 fl
  unsigned short* hwb  = (unsigned short*)(ws + 1525312);   // 1048576 fl
  float* xgT   = ws + 2573888;             // 6553600 fl, ends 9127488
  float* cbuf  = part;                     // overlay: part dead after pool_ctx
  float* out   = (float*)d_out;            // (64,50,4096)

  k_conv<<<2048, 512, 0, stream>>>(mask, w1, b1, w2, b2, part);
  k_prep<<<3072, 256, 0, stream>>>(w_ih, head_w, wihb, hwb, flags);
  k_pool_ctx<<<64, 256, 0, stream>>>(part, feat_w, feat_b, ctx_w, ctx_b,
                                     hbuf, h0f, ctx);
  k_build_A<<<3200, 128, 0, stream>>>(temb, tgt, ctx, Ab16);
  k_gemm_mfma<0><<<25 * 16, 256, 0, stream>>>(Ab16, wihb, b_ih, b_hh, xgT, 16);

  // Persistent MFMA LSTM (cooperative -> co-residency guaranteed, hang-proof).
  {
    const float* xgT_c = xgT;
    const float* whh_c = w_hh_p;
    const unsigned short* h0f_c = h0f;
    unsigned short* hallf_c = hallf;
    int* flags_c = flags;
    void* args[] = {(void*)&xgT_c, (void*)&whh_c, (void*)&h0f_c,
                    (void*)&hallf_c, (void*)&flags_c};
    hipError_t e = hipLaunchCooperativeKernel(
        (const void*)k_lstm_mfma, dim3(LSTM_NB), dim3(256), args, 0, stream);
    if (e != hipSuccess) {
      (void)hipGetLastError();  // clear sticky error
      k_zero_f<<<128, 256, 0, stream>>>(cbuf);
      for (int t = 0; t < 50; t++) {
        const float* hin = hbuf + (t & 1) * 32768;
        float* hout = hbuf + ((t + 1) & 1) * 32768;
        k_lstm_step1<<<256, 256, 0, stream>>>(
            xgT, w_hh_p, hin, hout, hallf + (size_t)t * 32768, cbuf, t);
      }
    }
  }

  k_gemm_mfma<1><<<25 * 32, 256, 0, stream>>>(hallf, hwb, head_b, nullptr, out, 32);
}